// Round 10
// baseline (423.728 us; speedup 1.0000x reference)
//
#include <hip/hip_runtime.h>
#include <hip/hip_bf16.h>

#define D 64
#define KH 5
#define KS 6                        // chunk-list depth: pos + top-5 coverage
#define TILE 64
#define TPC 8                       // tiles per chunk (LDS-resident)
#define CHUNK_ITEMS 512             // 64 KB fp16 in LDS
#define NCH 196                     // ceil(100000/512); 196*512 = 100352
#define NSUB 32                     // sub-tile (16-item) maxes per chunk
#define TMPAD 33                    // TM stride (odd)
#define CAP 28                      // candidate cap per (row,chunk)
#define CAPP 29                     // CV/CI stride
#define BM 64                       // user-rows per block
#define NCAND (NCH * KS)            // 1176 candidates per row at finalize

typedef _Float16 half8 __attribute__((ext_vector_type(8)));
typedef float f32x4 __attribute__((ext_vector_type(4)));

__device__ __forceinline__ bool better(float v, int vi, float w, int wi) {
    return (v > w) || (v == w && vi < wi);
}

__device__ __forceinline__ void top5_insert(float (&v)[KH], int (&ix)[KH], float nv, int ni) {
    if (better(nv, ni, v[KH - 1], ix[KH - 1])) {
        v[KH - 1] = nv; ix[KH - 1] = ni;
#pragma unroll
        for (int j = KH - 1; j > 0; --j) {
            if (better(v[j], ix[j], v[j - 1], ix[j - 1])) {
                float tf = v[j]; v[j] = v[j - 1]; v[j - 1] = tf;
                int   tI = ix[j]; ix[j] = ix[j - 1]; ix[j - 1] = tI;
            }
        }
    }
}

__device__ __forceinline__ void gload_lds16(const void* g, void* l) {
    __builtin_amdgcn_global_load_lds(
        (const __attribute__((address_space(1))) unsigned int*)g,
        (__attribute__((address_space(3))) unsigned int*)l, 16, 0, 0);
}

// ---------- prep: normalized fp16 table H[N][64] + fp32 inv_norm[N] ----------
__global__ void prep_kernel(const float* __restrict__ emb,
                            _Float16* __restrict__ H,
                            float* __restrict__ inv_norm, int N) {
    int tid = threadIdx.x;
    int wave = tid >> 6, lane = tid & 63;
    int item = blockIdx.x * 16 + wave * 4 + (lane >> 4);
    if (item >= N) return;
    int g = lane & 15;
    float4 v = reinterpret_cast<const float4*>(emb)[item * 16 + g];
    float ss = v.x * v.x + v.y * v.y + v.z * v.z + v.w * v.w;
#pragma unroll
    for (int m = 1; m < 16; m <<= 1) ss += __shfl_xor(ss, m, 64);
    float inv = 1.0f / fmaxf(sqrtf(ss), 1e-12f);
    union { _Float16 h[4]; uint2 u; } pk;
    pk.h[0] = (_Float16)(v.x * inv);
    pk.h[1] = (_Float16)(v.y * inv);
    pk.h[2] = (_Float16)(v.z * inv);
    pk.h[3] = (_Float16)(v.w * inv);
    reinterpret_cast<uint2*>(H)[item * 16 + g] = pk.u;
    if (g == 0) inv_norm[item] = inv;
}

// ---------- main: LDS-resident chunk, two-pass sub-tile-max thresholding ----------
// grid 6272 = 32 rowblocks x 196 chunks; block 256 = 4 waves; 2 blocks/CU.
// Wave w owns tiles w and w+4: stages them once (gload_lds + counted vmcnt),
// then both passes read LDS only. Split accumulators double MFMA ILP.
__global__ __launch_bounds__(256, 2)
void simtopk_kernel(const _Float16* __restrict__ H,
                    const int* __restrict__ pos_items,
                    int* __restrict__ part_idx, int N) {
    __shared__ __align__(16) unsigned char IT[TPC * 8192];        // 64 KB items
    __shared__ __align__(16) unsigned char UN[BM * CAPP * 8];     // CV|CI; TM overlays
    __shared__ float TH[BM];
    __shared__ int   CNT[BM];

    float (*TM)[TMPAD] = (float (*)[TMPAD])UN;                    // pass 1 [64][33]
    float* CV = (float*)UN;                                       // pass 2 [64][29]
    int*   CI = (int*)(UN + BM * CAPP * 4);

    const int tid = threadIdx.x;
    const int w = tid >> 6, lane = tid & 63;
    const int l15 = lane & 15, l4 = lane >> 4;

    const int id = blockIdx.x;
    const int rb = id & 31;            // 32 rowblocks (consecutive ids share chunk)
    const int ch = id >> 5;            // 196 chunks
    const int row0 = rb * BM;
    const int cbeg = ch * CHUNK_ITEMS;

    // B fragments: 4 groups x 16 user rows, register-resident
    half8 b0[4], b1[4];
#pragma unroll
    for (int g = 0; g < 4; ++g) {
        int ap = pos_items[row0 + g * 16 + l15];
        const half8* Hrow = (const half8*)(H + (size_t)ap * D);
        b0[g] = Hrow[l4];
        b1[g] = Hrow[4 + l4];
    }

    // stage one 64-item tile (8KB) into IT slot t: linear LDS dest, pre-swizzled src
#define STAGE(t)                                                        \
    {                                                                   \
        int ib_ = cbeg + (t) * TILE;                                    \
        _Pragma("unroll")                                               \
        for (int i = 0; i < 8; ++i) {                                   \
            int r_ = i * 8 + (lane >> 3);                               \
            int j_ = lane & 7;                                          \
            int grow_ = min(ib_ + r_, N - 1);                           \
            const char* src_ = (const char*)H + (size_t)grow_ * 128 +   \
                               ((j_ ^ (r_ & 7)) << 4);                  \
            gload_lds16(src_, (void*)(IT + (t) * 8192 + i * 1024));     \
        }                                                               \
    }

// pass-1 body for tile t: per-(row,16-item-subtile) max, branchless
#define P1TILE(t)                                                       \
    {                                                                   \
        const unsigned char* base_ = IT + (t) * 8192;                   \
        const int ibase_ = cbeg + (t) * TILE;                           \
        const bool ragged_ = (ibase_ + TILE > N);                       \
        _Pragma("unroll")                                               \
        for (int sub = 0; sub < 4; ++sub) {                             \
            const int r_ = sub * 16 + l15;                              \
            const int sw_ = l15 & 7;                                    \
            half8 a0 = *(const half8*)(base_ + r_ * 128 + ((l4 ^ sw_) << 4));        \
            half8 a1 = *(const half8*)(base_ + r_ * 128 + (((4 + l4) ^ sw_) << 4));  \
            const int bn_ = ibase_ + sub * 16 + 4 * l4;                 \
            _Pragma("unroll")                                           \
            for (int g = 0; g < 4; ++g) {                               \
                f32x4 z_ = {0.f, 0.f, 0.f, 0.f};                        \
                f32x4 c0_ = __builtin_amdgcn_mfma_f32_16x16x32_f16(a0, b0[g], z_, 0, 0, 0); \
                f32x4 c1_ = __builtin_amdgcn_mfma_f32_16x16x32_f16(a1, b1[g], z_, 0, 0, 0); \
                float S_[4];                                            \
                _Pragma("unroll")                                       \
                for (int q = 0; q < 4; ++q) {                           \
                    S_[q] = c0_[q] + c1_[q];                            \
                    if (ragged_ && bn_ + q >= N) S_[q] = -3e38f;        \
                }                                                       \
                float m4_ = fmaxf(fmaxf(S_[0], S_[1]), fmaxf(S_[2], S_[3]));  \
                m4_ = fmaxf(m4_, __shfl_xor(m4_, 16, 64));              \
                m4_ = fmaxf(m4_, __shfl_xor(m4_, 32, 64));              \
                if (l4 == 0) TM[g * 16 + l15][(t) * 4 + sub] = m4_;     \
            }                                                           \
        }                                                               \
    }

// pass-2 body for tile t: collect scores >= theta (identical arithmetic)
#define P2TILE(t)                                                       \
    {                                                                   \
        const unsigned char* base_ = IT + (t) * 8192;                   \
        const int ibase_ = cbeg + (t) * TILE;                           \
        const bool ragged_ = (ibase_ + TILE > N);                       \
        _Pragma("unroll")                                               \
        for (int sub = 0; sub < 4; ++sub) {                             \
            const int r_ = sub * 16 + l15;                              \
            const int sw_ = l15 & 7;                                    \
            half8 a0 = *(const half8*)(base_ + r_ * 128 + ((l4 ^ sw_) << 4));        \
            half8 a1 = *(const half8*)(base_ + r_ * 128 + (((4 + l4) ^ sw_) << 4));  \
            const int bn_ = ibase_ + sub * 16 + 4 * l4;                 \
            _Pragma("unroll")                                           \
            for (int g = 0; g < 4; ++g) {                               \
                f32x4 z_ = {0.f, 0.f, 0.f, 0.f};                        \
                f32x4 c0_ = __builtin_amdgcn_mfma_f32_16x16x32_f16(a0, b0[g], z_, 0, 0, 0); \
                f32x4 c1_ = __builtin_amdgcn_mfma_f32_16x16x32_f16(a1, b1[g], z_, 0, 0, 0); \
                float S_[4];                                            \
                _Pragma("unroll")                                       \
                for (int q = 0; q < 4; ++q) {                           \
                    S_[q] = c0_[q] + c1_[q];                            \
                    if (ragged_ && bn_ + q >= N) S_[q] = -3e38f;        \
                }                                                       \
                float m4_ = fmaxf(fmaxf(S_[0], S_[1]), fmaxf(S_[2], S_[3]));  \
                if (m4_ >= thg[g]) {                                    \
                    const int row_ = g * 16 + l15;                      \
                    _Pragma("unroll")                                   \
                    for (int q = 0; q < 4; ++q) {                       \
                        int n_ = bn_ + q;                               \
                        if (S_[q] >= thg[g] && n_ < N) {                \
                            int s_ = atomicAdd(&CNT[row_], 1);          \
                            if (s_ < CAP) { CV[row_ * CAPP + s_] = S_[q]; CI[row_ * CAPP + s_] = n_; } \
                        }                                               \
                    }                                                   \
                }                                                       \
            }                                                           \
        }                                                               \
    }

    // ---------------- pass 1: stage once + sub-tile maxes ----------------
    STAGE(w)
    STAGE(w + 4)
    asm volatile("s_waitcnt vmcnt(8)" ::: "memory");   // tile w staged
    P1TILE(w)
    asm volatile("s_waitcnt vmcnt(0)" ::: "memory");   // tile w+4 staged
    P1TILE(w + 4)

    __syncthreads();

    // threshold: row's 6th-highest sub-tile max (values-only network)
    float th_val;
    if (tid < BM) {
        float v[KS];
#pragma unroll
        for (int s = 0; s < KS; ++s) v[s] = -3e38f;
        for (int s = 0; s < NSUB; ++s) {
            float x = TM[tid][s];
            if (x > v[KS - 1]) {
                v[KS - 1] = x;
#pragma unroll
                for (int j = KS - 1; j > 0; --j) {
                    float lo = fminf(v[j], v[j - 1]);
                    v[j - 1] = fmaxf(v[j], v[j - 1]);
                    v[j] = lo;
                }
            }
        }
        th_val = v[KS - 1];
    }
    __syncthreads();          // TM reads done before CV/CI overwrite the union
    if (tid < BM) {
        TH[tid] = th_val;
        CNT[tid] = 0;
    }
    __syncthreads();

    float thg[4];
#pragma unroll
    for (int g = 0; g < 4; ++g) thg[g] = TH[g * 16 + l15];

    // ---------------- pass 2: from LDS only ----------------
    P2TILE(w)
    P2TILE(w + 4)

    __syncthreads();

    // trim: chunk top-6, write part_idx
    if (tid < BM) {
        int cnt = min(CNT[tid], CAP);
        float v[KS]; int ix[KS];
#pragma unroll
        for (int s = 0; s < KS; ++s) { v[s] = -3e38f; ix[s] = 0x7fffffff; }
        for (int s = 0; s < cnt; ++s) {
            float nv = CV[tid * CAPP + s]; int ni = CI[tid * CAPP + s];
            if (better(nv, ni, v[KS - 1], ix[KS - 1])) {
                v[KS - 1] = nv; ix[KS - 1] = ni;
#pragma unroll
                for (int j = KS - 1; j > 0; --j) {
                    if (better(v[j], ix[j], v[j - 1], ix[j - 1])) {
                        float tf = v[j]; v[j] = v[j - 1]; v[j - 1] = tf;
                        int   tI = ix[j]; ix[j] = ix[j - 1]; ix[j - 1] = tI;
                    }
                }
            }
        }
        int* dst = part_idx + (size_t)(row0 + tid) * NCAND + ch * KS;
#pragma unroll
        for (int s = 0; s < KS; ++s) dst[s] = ix[s];
    }
}

// ---------- finalize: exact fp32 re-rank, 16 candidates in parallel per wave ----------
__global__ void finalize_kernel(const float* __restrict__ emb,
                                const float* __restrict__ inv_norm,
                                const int* __restrict__ users,
                                const int* __restrict__ pos_items,
                                const int* __restrict__ part_idx,
                                int* __restrict__ out, int Bsz, int N) {
    const int w = threadIdx.x >> 6, lane = threadIdx.x & 63;
    const int b = blockIdx.x * 4 + w;
    if (b >= Bsz) return;
    const int p = pos_items[b], u = users[b];
    const int c = lane & 15, dq = lane >> 4;

    const float4* emb4 = (const float4*)emb;
    const float invp = inv_norm[p];
    float4 a[4];
#pragma unroll
    for (int q = 0; q < 4; ++q) {
        float4 t = emb4[(size_t)p * 16 + dq * 4 + q];
        a[q].x = t.x * invp; a[q].y = t.y * invp;
        a[q].z = t.z * invp; a[q].w = t.w * invp;
    }

    float tv[KH]; int ti_[KH];
#pragma unroll
    for (int s = 0; s < KH; ++s) { tv[s] = -3e38f; ti_[s] = 0x7fffffff; }

    const int* prow = part_idx + (size_t)b * NCAND;
    const int NIT = (NCAND + 15) / 16;

    for (int r = 0; r < NIT; ++r) {
        int ci = r * 16 + c;
        bool inb = (ci < NCAND);
        int idx = inb ? prow[ci] : 0x7fffffff;
        bool ok = inb && ((unsigned)idx < (unsigned)N) && (idx != p);
        int ic = ok ? idx : 0;
        float dot = 0.f;
#pragma unroll
        for (int q = 0; q < 4; ++q) {
            float4 x = emb4[(size_t)ic * 16 + dq * 4 + q];
            dot += a[q].x * x.x + a[q].y * x.y + a[q].z * x.z + a[q].w * x.w;
        }
        dot += __shfl_xor(dot, 16, 64);
        dot += __shfl_xor(dot, 32, 64);
        float val = ok ? dot * inv_norm[ic] : -3e38f;
        top5_insert(tv, ti_, val, ok ? idx : 0x7fffffff);
    }

#pragma unroll
    for (int m = 1; m <= 8; m <<= 1) {
        float ov[KH]; int oi[KH];
#pragma unroll
        for (int s = 0; s < KH; ++s) {
            ov[s] = __shfl_xor(tv[s], m, 64);
            oi[s] = __shfl_xor(ti_[s], m, 64);
        }
#pragma unroll
        for (int s = 0; s < KH; ++s) top5_insert(tv, ti_, ov[s], oi[s]);
    }

    if (lane == 0) {
        out[b] = u;
        out[Bsz + b] = p;
#pragma unroll
        for (int s = 0; s < KH; ++s) {
            out[2 * Bsz + b * KH + s] = u;
            out[2 * Bsz + KH * Bsz + b * KH + s] = ti_[s];
        }
    }
}

extern "C" void kernel_launch(void* const* d_in, const int* in_sizes, int n_in,
                              void* d_out, int out_size, void* d_ws, size_t ws_size,
                              hipStream_t stream) {
    const int*   users     = (const int*)d_in[0];
    const int*   pos_items = (const int*)d_in[1];
    const float* emb       = (const float*)d_in[3];

    const int B = in_sizes[0];
    const int N = in_sizes[3] / D;

    _Float16* H        = (_Float16*)d_ws;
    float*    inv_norm = (float*)((char*)d_ws + (size_t)N * D * 2);
    int*      part_idx = (int*)((char*)d_ws + (size_t)N * D * 2 + (size_t)N * 4);

    int* out = (int*)d_out;

    hipLaunchKernelGGL(prep_kernel, dim3((N + 15) / 16), dim3(256), 0, stream,
                       emb, H, inv_norm, N);

    hipLaunchKernelGGL(simtopk_kernel, dim3((B / BM) * NCH), dim3(256), 0, stream,
                       H, pos_items, part_idx, N);

    hipLaunchKernelGGL(finalize_kernel, dim3((B + 3) / 4), dim3(256), 0, stream,
                       emb, inv_norm, users, pos_items, part_idx, out, B, N);
}

// Round 11
// 157.291 us; speedup vs baseline: 2.6939x; 2.6939x over previous
//
#include <hip/hip_runtime.h>
#include <hip/hip_bf16.h>

#define D 64
#define KH 5
#define KS 6                        // chunk-list depth: pos + top-5 coverage
#define NCH 32                      // chunks
#define TPC 50                      // 64-item tiles per chunk
#define TILE 64
#define CHUNK_ITEMS (TPC * TILE)    // 3200; 32*3200 = 102400 >= N
#define NSUBCH (TPC * 2)            // 100 32-item block-maxes per chunk
#define TMP 105                     // TM stride (odd)
#define CAP 28                      // candidate cap per (row,chunk)
#define CAPP 29                     // CV/CI stride
#define BM 64                       // user-rows per block
#define NCAND (NCH * KS)            // 192 candidates per row at finalize

typedef _Float16 half8 __attribute__((ext_vector_type(8)));
typedef float f32x16 __attribute__((ext_vector_type(16)));

__device__ __forceinline__ bool better(float v, int vi, float w, int wi) {
    return (v > w) || (v == w && vi < wi);
}

__device__ __forceinline__ void top5_insert(float (&v)[KH], int (&ix)[KH], float nv, int ni) {
    if (better(nv, ni, v[KH - 1], ix[KH - 1])) {
        v[KH - 1] = nv; ix[KH - 1] = ni;
#pragma unroll
        for (int j = KH - 1; j > 0; --j) {
            if (better(v[j], ix[j], v[j - 1], ix[j - 1])) {
                float tf = v[j]; v[j] = v[j - 1]; v[j - 1] = tf;
                int   tI = ix[j]; ix[j] = ix[j - 1]; ix[j - 1] = tI;
            }
        }
    }
}

// ---------- prep: normalized fp16 table H[N][64] + fp32 inv_norm[N] ----------
__global__ void prep_kernel(const float* __restrict__ emb,
                            _Float16* __restrict__ H,
                            float* __restrict__ inv_norm, int N) {
    int tid = threadIdx.x;
    int wave = tid >> 6, lane = tid & 63;
    int item = blockIdx.x * 16 + wave * 4 + (lane >> 4);
    if (item >= N) return;
    int g = lane & 15;
    float4 v = reinterpret_cast<const float4*>(emb)[item * 16 + g];
    float ss = v.x * v.x + v.y * v.y + v.z * v.z + v.w * v.w;
#pragma unroll
    for (int m = 1; m < 16; m <<= 1) ss += __shfl_xor(ss, m, 64);
    float inv = 1.0f / fmaxf(sqrtf(ss), 1e-12f);
    union { _Float16 h[4]; uint2 u; } pk;
    pk.h[0] = (_Float16)(v.x * inv);
    pk.h[1] = (_Float16)(v.y * inv);
    pk.h[2] = (_Float16)(v.z * inv);
    pk.h[3] = (_Float16)(v.w * inv);
    reinterpret_cast<uint2*>(H)[item * 16 + g] = pk.u;
    if (g == 0) inv_norm[item] = inv;
}

// ---------- main: two-pass 32-item-block-max thresholding, 32x32x16 MFMA ----------
// grid 1024 (XCD-swizzled (rowblock, chunk)), block 256 = 4 waves.
// Wave w handles 64-item tiles w, w+4, ...; 64 pos rows register-resident.
// acc layout (A=items, B=pos): col(lane&31)=user row, row=(r&3)+8*(r>>2)+4*(lane>>5)=item.
__global__ __launch_bounds__(256, 2)
void simtopk_kernel(const _Float16* __restrict__ H,
                    const int* __restrict__ pos_items,
                    int* __restrict__ part_idx, int N) {
    // union{ TM[64][105] | CV[64][29]+CI[64][29] } + TH + CNT
    __shared__ __align__(16) unsigned char UN[BM * TMP * 4];
    __shared__ float TH[BM];
    __shared__ int   CNT[BM];
    float (*TM)[TMP] = (float (*)[TMP])UN;              // pass 1
    float* CV = (float*)UN;                             // pass 2 [64][29]
    int*   CI = (int*)(UN + BM * CAPP * 4);

    const int tid = threadIdx.x;
    const int w = tid >> 6, lane = tid & 63;
    const int l31 = lane & 31, l5 = lane >> 5;
    const int l5o = 4 * l5;

    // bijective XCD swizzle: ch%8 == blockIdx%8 == XCD -> L2-local item windows
    const int id = blockIdx.x;
    const int inner = id >> 3;
    const int ch = (id & 7) + 8 * (inner >> 5);
    const int rb = inner & 31;
    const int row0 = rb * BM;
    const int cbeg = ch * CHUNK_ITEMS;

    // B fragments: 2 row-blocks x 32 user rows x 4 K-steps (32 VGPR)
    half8 Bf[2][4];
#pragma unroll
    for (int r = 0; r < 2; ++r) {
        int ap = pos_items[row0 + r * 32 + l31];
        const half8* Hrow = (const half8*)(H + (size_t)ap * D);
#pragma unroll
        for (int s = 0; s < 4; ++s) Bf[r][s] = Hrow[2 * s + l5];
    }

    half8 A[2][4];
#define LOADA(t)                                                        \
    {                                                                   \
        int ib = cbeg + (t) * TILE;                                     \
        _Pragma("unroll")                                               \
        for (int ibk = 0; ibk < 2; ++ibk) {                             \
            int it = min(ib + ibk * 32 + l31, N - 1);                   \
            const half8* hp = (const half8*)(H + (size_t)it * D);       \
            _Pragma("unroll")                                           \
            for (int s = 0; s < 4; ++s) A[ibk][s] = hp[2 * s + l5];     \
        }                                                               \
    }

// one 32x32 output block: 4 chained MFMAs over K=64
#define MFMA_BLOCK(acc, ibk, rbk)                                       \
    f32x16 acc;                                                         \
    {                                                                   \
        _Pragma("unroll")                                               \
        for (int q = 0; q < 16; ++q) acc[q] = 0.0f;                     \
        _Pragma("unroll")                                               \
        for (int s = 0; s < 4; ++s)                                     \
            acc = __builtin_amdgcn_mfma_f32_32x32x16_f16(A[ibk][s], Bf[rbk][s], acc, 0, 0, 0); \
    }

    // ---------------- pass 1: per-(row, 32-item-block) max ----------------
    for (int t = w; t < TPC; t += 4) {
        LOADA(t);
        const int ibase = cbeg + t * TILE;
        const bool ragged = (ibase + TILE > N);
#pragma unroll
        for (int ibk = 0; ibk < 2; ++ibk) {
#pragma unroll
            for (int rbk = 0; rbk < 2; ++rbk) {
                MFMA_BLOCK(acc, ibk, rbk)
                const int bn = ibase + ibk * 32 + l5o;
                float m = -3e38f;
#pragma unroll
                for (int q = 0; q < 16; ++q) {
                    float s = acc[q];
                    if (ragged && (bn + ((q & 3) + 8 * (q >> 2)) >= N)) s = -3e38f;
                    m = fmaxf(m, s);
                }
                m = fmaxf(m, __shfl_xor(m, 32, 64));
                if (lane < 32) TM[rbk * 32 + lane][t * 2 + ibk] = m;
            }
        }
    }

    __syncthreads();

    // threshold: row's 6th-highest block-max (values-only sort network)
    float th_val;
    if (tid < BM) {
        float v[KS];
#pragma unroll
        for (int s = 0; s < KS; ++s) v[s] = -3e38f;
        for (int t = 0; t < NSUBCH; ++t) {
            float x = TM[tid][t];
            if (x > v[KS - 1]) {
                v[KS - 1] = x;
#pragma unroll
                for (int j = KS - 1; j > 0; --j) {
                    float lo = fminf(v[j], v[j - 1]);
                    v[j - 1] = fmaxf(v[j], v[j - 1]);
                    v[j] = lo;
                }
            }
        }
        th_val = v[KS - 1];
    }
    __syncthreads();          // TM reads done before CV/CI overwrite the union
    if (tid < BM) {
        TH[tid] = th_val;
        CNT[tid] = 0;
    }
    __syncthreads();

    float thg[2];
#pragma unroll
    for (int r = 0; r < 2; ++r) thg[r] = TH[r * 32 + l31];

    // ---------------- pass 2: collect scores >= theta (identical arithmetic) ----------------
    for (int t = w; t < TPC; t += 4) {
        LOADA(t);
        const int ibase = cbeg + t * TILE;
        const bool ragged = (ibase + TILE > N);
#pragma unroll
        for (int ibk = 0; ibk < 2; ++ibk) {
#pragma unroll
            for (int rbk = 0; rbk < 2; ++rbk) {
                MFMA_BLOCK(acc, ibk, rbk)
                const int bn = ibase + ibk * 32 + l5o;
                float m = -3e38f;
#pragma unroll
                for (int q = 0; q < 16; ++q) {
                    float s = acc[q];
                    if (ragged && (bn + ((q & 3) + 8 * (q >> 2)) >= N)) s = -3e38f;
                    m = fmaxf(m, s);
                }
                if (m >= thg[rbk]) {
                    const int row = rbk * 32 + l31;
#pragma unroll
                    for (int q = 0; q < 16; ++q) {
                        float s = acc[q];
                        int n = bn + ((q & 3) + 8 * (q >> 2));
                        if (ragged && n >= N) s = -3e38f;
                        if (s >= thg[rbk] && n < N) {
                            int sl = atomicAdd(&CNT[row], 1);
                            if (sl < CAP) { CV[row * CAPP + sl] = s; CI[row * CAPP + sl] = n; }
                        }
                    }
                }
            }
        }
    }

    __syncthreads();

    // trim: exact chunk top-6, write part_idx
    if (tid < BM) {
        int cnt = min(CNT[tid], CAP);
        float v[KS]; int ix[KS];
#pragma unroll
        for (int s = 0; s < KS; ++s) { v[s] = -3e38f; ix[s] = 0x7fffffff; }
        for (int s = 0; s < cnt; ++s) {
            float nv = CV[tid * CAPP + s]; int ni = CI[tid * CAPP + s];
            if (better(nv, ni, v[KS - 1], ix[KS - 1])) {
                v[KS - 1] = nv; ix[KS - 1] = ni;
#pragma unroll
                for (int j = KS - 1; j > 0; --j) {
                    if (better(v[j], ix[j], v[j - 1], ix[j - 1])) {
                        float tf = v[j]; v[j] = v[j - 1]; v[j - 1] = tf;
                        int   tI = ix[j]; ix[j] = ix[j - 1]; ix[j - 1] = tI;
                    }
                }
            }
        }
        int* dst = part_idx + (size_t)(row0 + tid) * NCAND + ch * KS;
#pragma unroll
        for (int s = 0; s < KS; ++s) dst[s] = ix[s];
    }
}

// ---------- finalize: exact fp32 re-rank, 16 candidates in parallel per wave ----------
__global__ void finalize_kernel(const float* __restrict__ emb,
                                const float* __restrict__ inv_norm,
                                const int* __restrict__ users,
                                const int* __restrict__ pos_items,
                                const int* __restrict__ part_idx,
                                int* __restrict__ out, int Bsz, int N) {
    const int w = threadIdx.x >> 6, lane = threadIdx.x & 63;
    const int b = blockIdx.x * 4 + w;
    if (b >= Bsz) return;
    const int p = pos_items[b], u = users[b];
    const int c = lane & 15, dq = lane >> 4;

    const float4* emb4 = (const float4*)emb;
    const float invp = inv_norm[p];
    float4 a[4];
#pragma unroll
    for (int q = 0; q < 4; ++q) {
        float4 t = emb4[(size_t)p * 16 + dq * 4 + q];
        a[q].x = t.x * invp; a[q].y = t.y * invp;
        a[q].z = t.z * invp; a[q].w = t.w * invp;
    }

    float tv[KH]; int ti_[KH];
#pragma unroll
    for (int s = 0; s < KH; ++s) { tv[s] = -3e38f; ti_[s] = 0x7fffffff; }

    const int* prow = part_idx + (size_t)b * NCAND;

    for (int r = 0; r < NCAND / 16; ++r) {
        int idx = prow[r * 16 + c];
        bool ok = ((unsigned)idx < (unsigned)N) && (idx != p);
        int ic = ok ? idx : 0;
        float dot = 0.f;
#pragma unroll
        for (int q = 0; q < 4; ++q) {
            float4 x = emb4[(size_t)ic * 16 + dq * 4 + q];
            dot += a[q].x * x.x + a[q].y * x.y + a[q].z * x.z + a[q].w * x.w;
        }
        dot += __shfl_xor(dot, 16, 64);
        dot += __shfl_xor(dot, 32, 64);
        float val = ok ? dot * inv_norm[ic] : -3e38f;
        top5_insert(tv, ti_, val, ok ? idx : 0x7fffffff);
    }

#pragma unroll
    for (int m = 1; m <= 8; m <<= 1) {
        float ov[KH]; int oi[KH];
#pragma unroll
        for (int s = 0; s < KH; ++s) {
            ov[s] = __shfl_xor(tv[s], m, 64);
            oi[s] = __shfl_xor(ti_[s], m, 64);
        }
#pragma unroll
        for (int s = 0; s < KH; ++s) top5_insert(tv, ti_, ov[s], oi[s]);
    }

    if (lane == 0) {
        out[b] = u;
        out[Bsz + b] = p;
#pragma unroll
        for (int s = 0; s < KH; ++s) {
            out[2 * Bsz + b * KH + s] = u;
            out[2 * Bsz + KH * Bsz + b * KH + s] = ti_[s];
        }
    }
}

extern "C" void kernel_launch(void* const* d_in, const int* in_sizes, int n_in,
                              void* d_out, int out_size, void* d_ws, size_t ws_size,
                              hipStream_t stream) {
    const int*   users     = (const int*)d_in[0];
    const int*   pos_items = (const int*)d_in[1];
    const float* emb       = (const float*)d_in[3];

    const int B = in_sizes[0];
    const int N = in_sizes[3] / D;

    _Float16* H        = (_Float16*)d_ws;
    float*    inv_norm = (float*)((char*)d_ws + (size_t)N * D * 2);
    int*      part_idx = (int*)((char*)d_ws + (size_t)N * D * 2 + (size_t)N * 4);

    int* out = (int*)d_out;

    hipLaunchKernelGGL(prep_kernel, dim3((N + 15) / 16), dim3(256), 0, stream,
                       emb, H, inv_norm, N);

    hipLaunchKernelGGL(simtopk_kernel, dim3((B / BM) * NCH), dim3(256), 0, stream,
                       H, pos_items, part_idx, N);

    hipLaunchKernelGGL(finalize_kernel, dim3((B + 3) / 4), dim3(256), 0, stream,
                       emb, inv_norm, users, pos_items, part_idx, out, B, N);
}